// Round 8
// baseline (415.566 us; speedup 1.0000x reference)
//
#include <hip/hip_runtime.h>
#include <hip/hip_bf16.h>
#include <math.h>

#define BB 8
#define SS 2048
#define HH 8
#define DKK 64
#define DM 512

typedef short bf16x8 __attribute__((ext_vector_type(8)));
typedef short bf16x4 __attribute__((ext_vector_type(4)));
typedef float f32x4 __attribute__((ext_vector_type(4)));
#define MFMA16(a, b, c) __builtin_amdgcn_mfma_f32_16x16x32_bf16(a, b, c, 0, 0, 0)

#if __has_builtin(__builtin_amdgcn_exp2f)
#define EXP2(x) __builtin_amdgcn_exp2f(x)
#else
#define EXP2(x) exp2f(x)
#endif

__device__ __forceinline__ unsigned short f2bf(float f) {
    __hip_bfloat16 h = __float2bfloat16(f);
    return *reinterpret_cast<unsigned short*>(&h);
}

__device__ __forceinline__ float max3f(float a, float b, float c) {
    return fmaxf(fmaxf(a, b), c);   // clang fuses to v_max3_f32
}

// Convert 8 consecutive fp32 -> 8 bf16, return as uint4 for a 16B LDS store.
__device__ __forceinline__ uint4 cvt8(const float* __restrict__ src) {
    float4 a = *(const float4*)src;
    float4 b = *(const float4*)(src + 4);
    unsigned short tmp[8];
    tmp[0] = f2bf(a.x); tmp[1] = f2bf(a.y); tmp[2] = f2bf(a.z); tmp[3] = f2bf(a.w);
    tmp[4] = f2bf(b.x); tmp[5] = f2bf(b.y); tmp[6] = f2bf(b.z); tmp[7] = f2bf(b.w);
    return *(uint4*)tmp;
}

// ---------------------------------------------------------------------------
// Mask bit-pack: mask int32 [S][S] -> mb uint64 [S][S/64], bit i of word
// (q, c) = (mask[q][c*64+i] != 0). One wave per output word via __ballot.
// ---------------------------------------------------------------------------
__global__ __launch_bounds__(256) void mask_pack(
    const int* __restrict__ mask, unsigned long long* __restrict__ mb)
{
    const int t = threadIdx.x;
    const int wid = (blockIdx.x << 2) | (t >> 6);   // global wave id == word idx
    const int lane = t & 63;
    const int q = wid >> 5;          // / (SS/64)
    const int c = wid & 31;
    int e = mask[(size_t)q * SS + (c << 6) + lane];
    unsigned long long bal = __ballot(e != 0);
    if (lane == 0) mb[wid] = bal;
}

// ---------------------------------------------------------------------------
// W pre-convert: Wq/Wk/Wv fp32 [512][512] -> bf16, same layout, packed into
// dst (3 x 262144 elems = 1.5 MB).
// ---------------------------------------------------------------------------
__global__ __launch_bounds__(256) void w_cvt(
    const float* __restrict__ Wq, const float* __restrict__ Wk,
    const float* __restrict__ Wv, unsigned short* __restrict__ dst)
{
    const int idx = blockIdx.x * 256 + threadIdx.x;   // 0..98303
    const int which = idx >> 15;                       // / 32768
    const int off = (idx & 32767) * 8;
    const float* src = (which == 0) ? Wq : (which == 1) ? Wk : Wv;
    *(uint4*)(dst + (size_t)which * 262144 + off) = cvt8(src + off);
}

// ---------------------------------------------------------------------------
// Fused QKV projection (gridDim.z selects Q/K/V): out[m][n] =
// (sum_k X[m][k]*W[n][k] + bias[n]) * scale. W comes PRE-CONVERTED bf16
// (uint4-copy staging); X is fp32 (cvt8 staging).
// z=0 (Q), z=1 (K): out bf16 scattered to [B*H][S][64] (n = h*64+d).
// z=2 (V): out written TRANSPOSED to [B*H][64][S].
// ---------------------------------------------------------------------------
__global__ __launch_bounds__(256, 2) void proj_qkv_fused(
    const float* __restrict__ Xq, const float* __restrict__ Xk, const float* __restrict__ Xv,
    const unsigned short* __restrict__ Wb,
    const float* __restrict__ bq, const float* __restrict__ bk, const float* __restrict__ bv,
    unsigned short* __restrict__ outbase, float qscale)
{
    const int z = blockIdx.z;
    const float* X = (z == 0) ? Xq : (z == 1) ? Xk : Xv;
    const unsigned short* W = Wb + (size_t)z * 262144;
    const float* bias = (z == 0) ? bq : (z == 1) ? bk : bv;
    unsigned short* out = outbase + (size_t)z * ((size_t)BB * HH * SS * DKK);
    const float scale = (z == 0) ? qscale : 1.0f;

    __shared__ __align__(16) unsigned short Xs[128][72];
    __shared__ __align__(16) unsigned short Ws[128][72];
    const int t = threadIdx.x;
    const int w = t >> 6, l = t & 63;
    const int l15 = l & 15, lg = l >> 4;
    const int n0 = blockIdx.x * 128, m0 = blockIdx.y * 128;
    const int mo = (w & 1) * 64, no = (w >> 1) * 64;

    f32x4 acc[4][4];
#pragma unroll
    for (int i = 0; i < 4; i++)
#pragma unroll
        for (int j = 0; j < 4; j++) acc[i][j] = (f32x4){0.f, 0.f, 0.f, 0.f};

    for (int k0 = 0; k0 < DM; k0 += 64) {
        __syncthreads();
#pragma unroll
        for (int rr = 0; rr < 4; rr++) {
            int idx = rr * 2048 + t * 8;
            int row = idx >> 6, col = idx & 63;
            *(uint4*)&Xs[row][col] = cvt8(X + (size_t)(m0 + row) * DM + k0 + col);
            *(uint4*)&Ws[row][col] = *(const uint4*)(W + (size_t)(n0 + row) * DM + k0 + col);
        }
        __syncthreads();

        bf16x8 af[4][2], bfr[4][2];
#pragma unroll
        for (int mt = 0; mt < 4; mt++) {
            af[mt][0] = *(const bf16x8*)&Xs[mo + mt * 16 + l15][lg * 8];
            af[mt][1] = *(const bf16x8*)&Xs[mo + mt * 16 + l15][32 + lg * 8];
        }
#pragma unroll
        for (int nt = 0; nt < 4; nt++) {
            bfr[nt][0] = *(const bf16x8*)&Ws[no + nt * 16 + l15][lg * 8];
            bfr[nt][1] = *(const bf16x8*)&Ws[no + nt * 16 + l15][32 + lg * 8];
        }
#pragma unroll
        for (int mt = 0; mt < 4; mt++)
#pragma unroll
            for (int nt = 0; nt < 4; nt++) {
                acc[mt][nt] = MFMA16(af[mt][0], bfr[nt][0], acc[mt][nt]);
                acc[mt][nt] = MFMA16(af[mt][1], bfr[nt][1], acc[mt][nt]);
            }
    }

    float bv4[4];
#pragma unroll
    for (int nt = 0; nt < 4; nt++) bv4[nt] = bias[n0 + no + nt * 16 + l15];

    const int h = (n0 + no) >> 6;
    if (z == 2) {
        // transposed V epilogue: vt[bh][d][s]
#pragma unroll
        for (int mt = 0; mt < 4; mt++) {
            int m = m0 + mo + mt * 16 + lg * 4;       // 4-aligned, never crosses b
            int bb = m >> 11, s = m & (SS - 1);
#pragma unroll
            for (int nt = 0; nt < 4; nt++) {
                int d = nt * 16 + l15;
                bf16x4 pk;
#pragma unroll
                for (int r = 0; r < 4; r++) pk[r] = (short)f2bf(acc[mt][nt][r] + bv4[nt]);
                *(bf16x4*)(out + (((size_t)bb * HH + h) * DKK + d) * SS + s) = pk;
            }
        }
    } else {
#pragma unroll
        for (int mt = 0; mt < 4; mt++)
#pragma unroll
            for (int nt = 0; nt < 4; nt++)
#pragma unroll
                for (int r = 0; r < 4; r++) {
                    int m = m0 + mo + mt * 16 + lg * 4 + r;
                    int d = nt * 16 + l15;
                    float v = (acc[mt][nt][r] + bv4[nt]) * scale;
                    int bb = m >> 11, s = m & (SS - 1);
                    out[(((size_t)bb * HH + h) * SS + s) * 64 + d] = f2bf(v);
                }
    }
}

// ---------------------------------------------------------------------------
// Output projection: out[m][n] = sum_k A[m][k]*Wo[n][k] + bo[n]
// A bf16 [16384,512] (ws), Wo fp32 [512,512], out fp32 row-major (d_out).
// ---------------------------------------------------------------------------
__global__ __launch_bounds__(256, 2) void proj_out_mfma(
    const unsigned short* __restrict__ Xb,
    const float* __restrict__ W,
    const float* __restrict__ bias,
    float* __restrict__ out)
{
    __shared__ __align__(16) unsigned short Xs[128][72];
    __shared__ __align__(16) unsigned short Ws[128][72];
    const int t = threadIdx.x;
    const int w = t >> 6, l = t & 63;
    const int l15 = l & 15, lg = l >> 4;
    const int n0 = blockIdx.x * 128, m0 = blockIdx.y * 128;
    const int mo = (w & 1) * 64, no = (w >> 1) * 64;

    f32x4 acc[4][4];
#pragma unroll
    for (int i = 0; i < 4; i++)
#pragma unroll
        for (int j = 0; j < 4; j++) acc[i][j] = (f32x4){0.f, 0.f, 0.f, 0.f};

    for (int k0 = 0; k0 < DM; k0 += 64) {
        __syncthreads();
#pragma unroll
        for (int rr = 0; rr < 4; rr++) {
            int idx = rr * 2048 + t * 8;
            int row = idx >> 6, col = idx & 63;
            *(uint4*)&Xs[row][col] = *(const uint4*)(Xb + (size_t)(m0 + row) * DM + k0 + col);
            *(uint4*)&Ws[row][col] = cvt8(W + (size_t)(n0 + row) * DM + k0 + col);
        }
        __syncthreads();

        bf16x8 af[4][2], bfr[4][2];
#pragma unroll
        for (int mt = 0; mt < 4; mt++) {
            af[mt][0] = *(const bf16x8*)&Xs[mo + mt * 16 + l15][lg * 8];
            af[mt][1] = *(const bf16x8*)&Xs[mo + mt * 16 + l15][32 + lg * 8];
        }
#pragma unroll
        for (int nt = 0; nt < 4; nt++) {
            bfr[nt][0] = *(const bf16x8*)&Ws[no + nt * 16 + l15][lg * 8];
            bfr[nt][1] = *(const bf16x8*)&Ws[no + nt * 16 + l15][32 + lg * 8];
        }
#pragma unroll
        for (int mt = 0; mt < 4; mt++)
#pragma unroll
            for (int nt = 0; nt < 4; nt++) {
                acc[mt][nt] = MFMA16(af[mt][0], bfr[nt][0], acc[mt][nt]);
                acc[mt][nt] = MFMA16(af[mt][1], bfr[nt][1], acc[mt][nt]);
            }
    }

    float bv4[4];
#pragma unroll
    for (int nt = 0; nt < 4; nt++) bv4[nt] = bias[n0 + no + nt * 16 + l15];

#pragma unroll
    for (int mt = 0; mt < 4; mt++)
#pragma unroll
        for (int nt = 0; nt < 4; nt++)
#pragma unroll
            for (int r = 0; r < 4; r++) {
                int m = m0 + mo + mt * 16 + lg * 4 + r;
                int n = n0 + no + nt * 16 + l15;
                out[(size_t)m * DM + n] = acc[mt][nt][r] + bv4[nt];
            }
}

// ---------------------------------------------------------------------------
// Flash attention, bf16 MFMA. Block = (qblock of 256 rows) x (b,h), 512 thr.
// 8 waves; wave w owns q rows [w*32, w*32+32) (NQT=2). kv tiles of 64.
// ASYNC-STAGE SPLIT (T14): K/V tile t+1 global loads issue right after the
// staging barrier of tile t and are consumed at the next iteration's
// ds_write — HBM/L2 latency (~400-900 cyc) hides under tile t's compute.
// Rationale: occupancy is grid-capped at 2 blocks/CU (512 blocks); with TLP
// capped, the naked load->barrier->use chain was the dominant stall.
// S^T = K·Q^T; softmax exp2-domain; bit-packed mask; defer-max (THR=0).
// l via ones-column MFMA (Osum = P·1). Pw swizzled, wave-private.
// __launch_bounds__(512,4): VGPR was 64, +8 for the in-flight tile regs.
// ---------------------------------------------------------------------------
__global__ __launch_bounds__(512, 4) void attn_kernel(
    const unsigned short* __restrict__ qw, const unsigned short* __restrict__ kw,
    const unsigned short* __restrict__ vtw,
    const unsigned long long* __restrict__ mb,
    unsigned short* __restrict__ ao)   // [B,S,512] bf16
{
    __shared__ __align__(16) unsigned short Ks[64][72];   // [kv][d]
    __shared__ __align__(16) unsigned short Vt[64][72];   // [d][kv]
    __shared__ __align__(16) unsigned short Pw[8 * 32 * 64]; // per-wave [q][kv] swizzled
    const int t = threadIdx.x;
    const int w = t >> 6, l = t & 63;
    const int l15 = l & 15, lg = l >> 4;
    const int q0 = blockIdx.x * 256;
    const int bh = blockIdx.y;
    const int b = bh >> 3, h = bh & 7;
    const int q0w = q0 + w * 32;
    const unsigned short* qb = qw + (size_t)bh * SS * DKK;
    const unsigned short* kb = kw + (size_t)bh * SS * DKK;
    const unsigned short* vtb = vtw + (size_t)bh * DKK * SS;

    // Per-qt bit-mask row base (row = q0w + qt*16 + l15; 32 words per row)
    const unsigned long long* mbq[2];
#pragma unroll
    for (int qt = 0; qt < 2; qt++)
        mbq[qt] = mb + ((size_t)(q0w + qt * 16 + l15) << 5);

    // Q fragments (B-operand): Qf[qt][dh] = Q[q0w+qt*16+l15][dh*32+lg*8 ..+8]
    bf16x8 Qf[2][2];
#pragma unroll
    for (int qt = 0; qt < 2; qt++)
#pragma unroll
        for (int dh = 0; dh < 2; dh++)
            Qf[qt][dh] = *(const bf16x8*)(qb + (size_t)(q0w + qt * 16 + l15) * DKK + dh * 32 + lg * 8);

    f32x4 O[2][4];    // [qt][dt]: row q = qt*16+lg*4+r, col d = dt*16+l15
    f32x4 Osum[2];    // ones-column accumulator: row sums of P (l denominator)
#pragma unroll
    for (int i = 0; i < 2; i++) {
#pragma unroll
        for (int j = 0; j < 4; j++) O[i][j] = (f32x4){0.f, 0.f, 0.f, 0.f};
        Osum[i] = (f32x4){0.f, 0.f, 0.f, 0.f};
    }
    float m_i[2];
#pragma unroll
    for (int i = 0; i < 2; i++) m_i[i] = -INFINITY;

    const bf16x8 vone = {16256, 16256, 16256, 16256, 16256, 16256, 16256, 16256}; // bf16 1.0 x8
    const int pbase = w * 2048;

    // Per-thread staging coordinates (1 uint4 per buffer per tile)
    const int srow = t >> 3;            // 0..63
    const int scol = (t & 7) * 8;       // 0..56

    // ---- prologue: preload tile 0 into registers ----
    uint4 kreg = *(const uint4*)(kb + (size_t)srow * DKK + scol);
    uint4 vreg = *(const uint4*)(vtb + (size_t)srow * SS + scol);

    for (int kv0 = 0; kv0 < SS; kv0 += 64) {
        __syncthreads();   // all waves done reading Ks/Vt of previous tile
        // ---- write the in-flight tile to LDS ----
        *(uint4*)&Ks[srow][scol] = kreg;
        *(uint4*)&Vt[srow][scol] = vreg;
        __syncthreads();

        // ---- issue next tile's global loads NOW; consumed next iteration,
        //      latency hides under this tile's QK^T/softmax/PV ----
        if (kv0 + 64 < SS) {
            kreg = *(const uint4*)(kb + (size_t)(kv0 + 64 + srow) * DKK + scol);
            vreg = *(const uint4*)(vtb + (size_t)srow * SS + (kv0 + 64) + scol);
        }

        // ---- S^T = K·Q^T : S[kvt][qt], row kv = kvt*16+lg*4+r, col q = qt*16+l15
        f32x4 S[4][2];
#pragma unroll
        for (int kvt = 0; kvt < 4; kvt++) {
            bf16x8 ak0 = *(const bf16x8*)&Ks[kvt * 16 + l15][lg * 8];
            bf16x8 ak1 = *(const bf16x8*)&Ks[kvt * 16 + l15][32 + lg * 8];
#pragma unroll
            for (int qt = 0; qt < 2; qt++) {
                f32x4 z = (f32x4){0.f, 0.f, 0.f, 0.f};
                z = MFMA16(ak0, Qf[qt][0], z);
                z = MFMA16(ak1, Qf[qt][1], z);
                S[kvt][qt] = z;
            }
        }

        // ---- mask via packed bits: bit kv_local = kvt*16 + lg*4 + r ----
#pragma unroll
        for (int qt = 0; qt < 2; qt++) {
            unsigned long long mm = mbq[qt][kv0 >> 6];
            unsigned int wlo = (unsigned int)mm;
            unsigned int whi = (unsigned int)(mm >> 32);
            unsigned int u[4];
            u[0] = wlo >> (lg * 4);
            u[1] = wlo >> (16 + lg * 4);
            u[2] = whi >> (lg * 4);
            u[3] = whi >> (16 + lg * 4);
#pragma unroll
            for (int kvt = 0; kvt < 4; kvt++) {
                if (!(u[kvt] & 1u)) S[kvt][qt][0] = -1e38f;
                if (!(u[kvt] & 2u)) S[kvt][qt][1] = -1e38f;
                if (!(u[kvt] & 4u)) S[kvt][qt][2] = -1e38f;
                if (!(u[kvt] & 8u)) S[kvt][qt][3] = -1e38f;
            }
        }

        // ---- online softmax (exp2 domain) with defer-max (THR=0) ----
        float mtl[2];
#pragma unroll
        for (int qt = 0; qt < 2; qt++) {
            // balanced max3 tree over the 16 values (v_max3_f32 fusion)
            float mt = fmaxf(
                max3f(max3f(S[0][qt][0], S[0][qt][1], S[0][qt][2]),
                      max3f(S[0][qt][3], S[1][qt][0], S[1][qt][1]),
                      max3f(S[1][qt][2], S[1][qt][3], S[2][qt][0])),
                fmaxf(max3f(S[2][qt][1], S[2][qt][2], S[2][qt][3]),
                      max3f(S[3][qt][0], S[3][qt][1], fmaxf(S[3][qt][2], S[3][qt][3]))));
            mt = fmaxf(mt, __shfl_xor(mt, 16));
            mt = fmaxf(mt, __shfl_xor(mt, 32));
            mtl[qt] = mt;
        }
        int grow = (mtl[0] > m_i[0]) | (mtl[1] > m_i[1]);
        if (__any(grow)) {
            float alpha[2];
#pragma unroll
            for (int qt = 0; qt < 2; qt++) {
                float mn = fmaxf(m_i[qt], mtl[qt]);
                alpha[qt] = EXP2(m_i[qt] - mn);
                m_i[qt] = mn;
            }
            // rescale O and Osum by alpha (broadcast from q-col lanes to q-row regs)
#pragma unroll
            for (int qt = 0; qt < 2; qt++)
#pragma unroll
                for (int r = 0; r < 4; r++) {
                    float a = __shfl(alpha[qt], lg * 4 + r);
#pragma unroll
                    for (int dt = 0; dt < 4; dt++) O[qt][dt][r] *= a;
                    Osum[qt][r] *= a;
                }
        }

#pragma unroll
        for (int qt = 0; qt < 2; qt++) {
            const int prow = qt * 16 + l15;
            const int swz = (prow & 7) << 3;
#pragma unroll
            for (int kvt = 0; kvt < 4; kvt++) {
                float p0 = EXP2(S[kvt][qt][0] - m_i[qt]);
                float p1 = EXP2(S[kvt][qt][1] - m_i[qt]);
                float p2 = EXP2(S[kvt][qt][2] - m_i[qt]);
                float p3 = EXP2(S[kvt][qt][3] - m_i[qt]);
                bf16x4 pk;
                pk[0] = (short)f2bf(p0); pk[1] = (short)f2bf(p1);
                pk[2] = (short)f2bf(p2); pk[3] = (short)f2bf(p3);
                *(bf16x4*)&Pw[pbase + prow * 64 + ((kvt * 16 + lg * 4) ^ swz)] = pk;
            }
        }

        // Pw is wave-private: per-wave DS ops complete in order, so a block
        // barrier is unnecessary. The fence stops the compiler from hoisting
        // the ap reads above the pk stores.
        asm volatile("s_waitcnt lgkmcnt(0)" ::: "memory");

        // ---- O += P·V ; Osum += P·1 (row sums == softmax denominator) ----
        bf16x8 bv2[4][2];
#pragma unroll
        for (int dt = 0; dt < 4; dt++) {
            bv2[dt][0] = *(const bf16x8*)&Vt[dt * 16 + l15][lg * 8];
            bv2[dt][1] = *(const bf16x8*)&Vt[dt * 16 + l15][32 + lg * 8];
        }
#pragma unroll
        for (int qt = 0; qt < 2; qt++) {
            const int prow = qt * 16 + l15;
            const int swz = (prow & 7) << 3;
            bf16x8 ap0 = *(const bf16x8*)&Pw[pbase + prow * 64 + ((lg * 8) ^ swz)];
            bf16x8 ap1 = *(const bf16x8*)&Pw[pbase + prow * 64 + ((32 + lg * 8) ^ swz)];
#pragma unroll
            for (int dt = 0; dt < 4; dt++) {
                O[qt][dt] = MFMA16(ap0, bv2[dt][0], O[qt][dt]);
                O[qt][dt] = MFMA16(ap1, bv2[dt][1], O[qt][dt]);
            }
            Osum[qt] = MFMA16(ap0, vone, Osum[qt]);
            Osum[qt] = MFMA16(ap1, vone, Osum[qt]);
        }
    }

    // ---- epilogue: normalize by Osum (per-lane, no shfl), store bf16 ----
#pragma unroll
    for (int qt = 0; qt < 2; qt++) {
#pragma unroll
        for (int r = 0; r < 4; r++) {
            float lv = 1.f / Osum[qt][r];
            int q = q0w + qt * 16 + lg * 4 + r;
            size_t base = ((size_t)b * SS + q) * DM + h * 64;
#pragma unroll
            for (int dt = 0; dt < 4; dt++)
                ao[base + dt * 16 + l15] = f2bf(O[qt][dt][r] * lv);
        }
    }
}

extern "C" void kernel_launch(void* const* d_in, const int* in_sizes, int n_in,
                              void* d_out, int out_size, void* d_ws, size_t ws_size,
                              hipStream_t stream) {
    // All float tensors are fp32 (proven). mask is int32.
    const float* Q    = (const float*)d_in[0];
    const float* K    = (const float*)d_in[1];
    const float* V    = (const float*)d_in[2];
    const int*   mask = (const int*)d_in[3];
    const float* Wq   = (const float*)d_in[4];
    const float* bq   = (const float*)d_in[5];
    const float* Wk   = (const float*)d_in[6];
    const float* bk   = (const float*)d_in[7];
    const float* Wv   = (const float*)d_in[8];
    const float* bv   = (const float*)d_in[9];
    const float* Wo   = (const float*)d_in[10];
    const float* bo   = (const float*)d_in[11];

    // ws: [qb 16 MB][kb 16 MB][vtb 16 MB][ab 16 MB] = 64 MB (proven-safe).
    // vtb holds V ALREADY TRANSPOSED ([bh][64][S]). ab head doubles as the
    // bf16-W scratch (1.5 MB): written by w_cvt, read by proj_qkv_fused,
    // then fully overwritten by attn's output (stream-ordered, safe).
    const size_t SEG = (size_t)BB * HH * SS * DKK;  // 8,388,608 bf16 elems
    unsigned short* qb  = (unsigned short*)d_ws;
    unsigned short* kb  = qb + SEG;
    unsigned short* vtb = kb + SEG;
    unsigned short* ab  = vtb + SEG;
    unsigned short* wb  = ab;   // 3 x 262144 bf16 = 1.5 MB, dead before attn

    const size_t MB_BYTES = (size_t)SS * (SS / 64) * sizeof(unsigned long long); // 524288
    unsigned long long* mbits =
        (unsigned long long*)((char*)d_out + (size_t)out_size - MB_BYTES);

    const float qscale = 0.125f * 1.44269504088896340736f;  // 1/sqrt(dk) * log2(e)

    mask_pack<<<dim3((SS * (SS / 64)) / 4), 256, 0, stream>>>(mask, mbits);
    w_cvt<<<dim3(384), 256, 0, stream>>>(Wq, Wk, Wv, wb);

    dim3 gp(DM / 128, (BB * SS) / 128, 3);  // (4, 128, 3)
    proj_qkv_fused<<<gp, 256, 0, stream>>>(Q, K, V, wb, bq, bk, bv, qb, qscale);

    attn_kernel<<<dim3(SS / 256, BB * HH), 512, 0, stream>>>(qb, kb, vtb, mbits, ab);

    proj_out_mfma<<<dim3(DM / 128, (BB * SS) / 128), 256, 0, stream>>>(ab, Wo, bo, (float*)d_out);
}

// Round 9
// 387.382 us; speedup vs baseline: 1.0728x; 1.0728x over previous
//
#include <hip/hip_runtime.h>
#include <hip/hip_bf16.h>
#include <math.h>

#define BB 8
#define SS 2048
#define HH 8
#define DKK 64
#define DM 512

typedef short bf16x8 __attribute__((ext_vector_type(8)));
typedef short bf16x4 __attribute__((ext_vector_type(4)));
typedef float f32x4 __attribute__((ext_vector_type(4)));
#define MFMA16(a, b, c) __builtin_amdgcn_mfma_f32_16x16x32_bf16(a, b, c, 0, 0, 0)

#if __has_builtin(__builtin_amdgcn_exp2f)
#define EXP2(x) __builtin_amdgcn_exp2f(x)
#else
#define EXP2(x) exp2f(x)
#endif

// async global->LDS, 16B per lane; lds dest must be wave-uniform base
// (HW writes base + lane*16). Global src IS per-lane (pre-swizzled here).
#define GLL16(gsrc, ldst)                                                      \
    __builtin_amdgcn_global_load_lds(                                          \
        (const __attribute__((address_space(1))) unsigned int*)(gsrc),         \
        (__attribute__((address_space(3))) unsigned int*)(ldst), 16, 0, 0)

__device__ __forceinline__ unsigned short f2bf(float f) {
    __hip_bfloat16 h = __float2bfloat16(f);
    return *reinterpret_cast<unsigned short*>(&h);
}

__device__ __forceinline__ float max3f(float a, float b, float c) {
    return fmaxf(fmaxf(a, b), c);   // clang fuses to v_max3_f32
}

// Convert 8 consecutive fp32 -> 8 bf16, return as uint4 for a 16B LDS store.
__device__ __forceinline__ uint4 cvt8(const float* __restrict__ src) {
    float4 a = *(const float4*)src;
    float4 b = *(const float4*)(src + 4);
    unsigned short tmp[8];
    tmp[0] = f2bf(a.x); tmp[1] = f2bf(a.y); tmp[2] = f2bf(a.z); tmp[3] = f2bf(a.w);
    tmp[4] = f2bf(b.x); tmp[5] = f2bf(b.y); tmp[6] = f2bf(b.z); tmp[7] = f2bf(b.w);
    return *(uint4*)tmp;
}

// ---------------------------------------------------------------------------
// Mask bit-pack: mask int32 [S][S] -> mb uint64 [S][S/64], bit i of word
// (q, c) = (mask[q][c*64+i] != 0). One wave per output word via __ballot.
// ---------------------------------------------------------------------------
__global__ __launch_bounds__(256) void mask_pack(
    const int* __restrict__ mask, unsigned long long* __restrict__ mb)
{
    const int t = threadIdx.x;
    const int wid = (blockIdx.x << 2) | (t >> 6);   // global wave id == word idx
    const int lane = t & 63;
    const int q = wid >> 5;          // / (SS/64)
    const int c = wid & 31;
    int e = mask[(size_t)q * SS + (c << 6) + lane];
    unsigned long long bal = __ballot(e != 0);
    if (lane == 0) mb[wid] = bal;
}

// ---------------------------------------------------------------------------
// W pre-convert: Wq/Wk/Wv fp32 [512][512] -> bf16, same layout, packed into
// dst (3 x 262144 elems = 1.5 MB).
// ---------------------------------------------------------------------------
__global__ __launch_bounds__(256) void w_cvt(
    const float* __restrict__ Wq, const float* __restrict__ Wk,
    const float* __restrict__ Wv, unsigned short* __restrict__ dst)
{
    const int idx = blockIdx.x * 256 + threadIdx.x;   // 0..98303
    const int which = idx >> 15;                       // / 32768
    const int off = (idx & 32767) * 8;
    const float* src = (which == 0) ? Wq : (which == 1) ? Wk : Wv;
    *(uint4*)(dst + (size_t)which * 262144 + off) = cvt8(src + off);
}

// ---------------------------------------------------------------------------
// Fused QKV projection (gridDim.z selects Q/K/V): out[m][n] =
// (sum_k X[m][k]*W[n][k] + bias[n]) * scale. W comes PRE-CONVERTED bf16
// (uint4-copy staging); X is fp32 (cvt8 staging).
// z=0 (Q), z=1 (K): out bf16 scattered to [B*H][S][64] (n = h*64+d).
// z=2 (V): out written TRANSPOSED to [B*H][64][S].
// ---------------------------------------------------------------------------
__global__ __launch_bounds__(256, 2) void proj_qkv_fused(
    const float* __restrict__ Xq, const float* __restrict__ Xk, const float* __restrict__ Xv,
    const unsigned short* __restrict__ Wb,
    const float* __restrict__ bq, const float* __restrict__ bk, const float* __restrict__ bv,
    unsigned short* __restrict__ outbase, float qscale)
{
    const int z = blockIdx.z;
    const float* X = (z == 0) ? Xq : (z == 1) ? Xk : Xv;
    const unsigned short* W = Wb + (size_t)z * 262144;
    const float* bias = (z == 0) ? bq : (z == 1) ? bk : bv;
    unsigned short* out = outbase + (size_t)z * ((size_t)BB * HH * SS * DKK);
    const float scale = (z == 0) ? qscale : 1.0f;

    __shared__ __align__(16) unsigned short Xs[128][72];
    __shared__ __align__(16) unsigned short Ws[128][72];
    const int t = threadIdx.x;
    const int w = t >> 6, l = t & 63;
    const int l15 = l & 15, lg = l >> 4;
    const int n0 = blockIdx.x * 128, m0 = blockIdx.y * 128;
    const int mo = (w & 1) * 64, no = (w >> 1) * 64;

    f32x4 acc[4][4];
#pragma unroll
    for (int i = 0; i < 4; i++)
#pragma unroll
        for (int j = 0; j < 4; j++) acc[i][j] = (f32x4){0.f, 0.f, 0.f, 0.f};

    for (int k0 = 0; k0 < DM; k0 += 64) {
        __syncthreads();
#pragma unroll
        for (int rr = 0; rr < 4; rr++) {
            int idx = rr * 2048 + t * 8;
            int row = idx >> 6, col = idx & 63;
            *(uint4*)&Xs[row][col] = cvt8(X + (size_t)(m0 + row) * DM + k0 + col);
            *(uint4*)&Ws[row][col] = *(const uint4*)(W + (size_t)(n0 + row) * DM + k0 + col);
        }
        __syncthreads();

        bf16x8 af[4][2], bfr[4][2];
#pragma unroll
        for (int mt = 0; mt < 4; mt++) {
            af[mt][0] = *(const bf16x8*)&Xs[mo + mt * 16 + l15][lg * 8];
            af[mt][1] = *(const bf16x8*)&Xs[mo + mt * 16 + l15][32 + lg * 8];
        }
#pragma unroll
        for (int nt = 0; nt < 4; nt++) {
            bfr[nt][0] = *(const bf16x8*)&Ws[no + nt * 16 + l15][lg * 8];
            bfr[nt][1] = *(const bf16x8*)&Ws[no + nt * 16 + l15][32 + lg * 8];
        }
#pragma unroll
        for (int mt = 0; mt < 4; mt++)
#pragma unroll
            for (int nt = 0; nt < 4; nt++) {
                acc[mt][nt] = MFMA16(af[mt][0], bfr[nt][0], acc[mt][nt]);
                acc[mt][nt] = MFMA16(af[mt][1], bfr[nt][1], acc[mt][nt]);
            }
    }

    float bv4[4];
#pragma unroll
    for (int nt = 0; nt < 4; nt++) bv4[nt] = bias[n0 + no + nt * 16 + l15];

    const int h = (n0 + no) >> 6;
    if (z == 2) {
        // transposed V epilogue: vt[bh][d][s]
#pragma unroll
        for (int mt = 0; mt < 4; mt++) {
            int m = m0 + mo + mt * 16 + lg * 4;       // 4-aligned, never crosses b
            int bb = m >> 11, s = m & (SS - 1);
#pragma unroll
            for (int nt = 0; nt < 4; nt++) {
                int d = nt * 16 + l15;
                bf16x4 pk;
#pragma unroll
                for (int r = 0; r < 4; r++) pk[r] = (short)f2bf(acc[mt][nt][r] + bv4[nt]);
                *(bf16x4*)(out + (((size_t)bb * HH + h) * DKK + d) * SS + s) = pk;
            }
        }
    } else {
#pragma unroll
        for (int mt = 0; mt < 4; mt++)
#pragma unroll
            for (int nt = 0; nt < 4; nt++)
#pragma unroll
                for (int r = 0; r < 4; r++) {
                    int m = m0 + mo + mt * 16 + lg * 4 + r;
                    int d = nt * 16 + l15;
                    float v = (acc[mt][nt][r] + bv4[nt]) * scale;
                    int bb = m >> 11, s = m & (SS - 1);
                    out[(((size_t)bb * HH + h) * SS + s) * 64 + d] = f2bf(v);
                }
    }
}

// ---------------------------------------------------------------------------
// Output projection: out[m][n] = sum_k A[m][k]*Wo[n][k] + bo[n]
// A bf16 [16384,512] (ws), Wo fp32 [512,512], out fp32 row-major (d_out).
// ---------------------------------------------------------------------------
__global__ __launch_bounds__(256, 2) void proj_out_mfma(
    const unsigned short* __restrict__ Xb,
    const float* __restrict__ W,
    const float* __restrict__ bias,
    float* __restrict__ out)
{
    __shared__ __align__(16) unsigned short Xs[128][72];
    __shared__ __align__(16) unsigned short Ws[128][72];
    const int t = threadIdx.x;
    const int w = t >> 6, l = t & 63;
    const int l15 = l & 15, lg = l >> 4;
    const int n0 = blockIdx.x * 128, m0 = blockIdx.y * 128;
    const int mo = (w & 1) * 64, no = (w >> 1) * 64;

    f32x4 acc[4][4];
#pragma unroll
    for (int i = 0; i < 4; i++)
#pragma unroll
        for (int j = 0; j < 4; j++) acc[i][j] = (f32x4){0.f, 0.f, 0.f, 0.f};

    for (int k0 = 0; k0 < DM; k0 += 64) {
        __syncthreads();
#pragma unroll
        for (int rr = 0; rr < 4; rr++) {
            int idx = rr * 2048 + t * 8;
            int row = idx >> 6, col = idx & 63;
            *(uint4*)&Xs[row][col] = *(const uint4*)(Xb + (size_t)(m0 + row) * DM + k0 + col);
            *(uint4*)&Ws[row][col] = cvt8(W + (size_t)(n0 + row) * DM + k0 + col);
        }
        __syncthreads();

        bf16x8 af[4][2], bfr[4][2];
#pragma unroll
        for (int mt = 0; mt < 4; mt++) {
            af[mt][0] = *(const bf16x8*)&Xs[mo + mt * 16 + l15][lg * 8];
            af[mt][1] = *(const bf16x8*)&Xs[mo + mt * 16 + l15][32 + lg * 8];
        }
#pragma unroll
        for (int nt = 0; nt < 4; nt++) {
            bfr[nt][0] = *(const bf16x8*)&Ws[no + nt * 16 + l15][lg * 8];
            bfr[nt][1] = *(const bf16x8*)&Ws[no + nt * 16 + l15][32 + lg * 8];
        }
#pragma unroll
        for (int mt = 0; mt < 4; mt++)
#pragma unroll
            for (int nt = 0; nt < 4; nt++) {
                acc[mt][nt] = MFMA16(af[mt][0], bfr[nt][0], acc[mt][nt]);
                acc[mt][nt] = MFMA16(af[mt][1], bfr[nt][1], acc[mt][nt]);
            }
    }

    float bv4[4];
#pragma unroll
    for (int nt = 0; nt < 4; nt++) bv4[nt] = bias[n0 + no + nt * 16 + l15];

#pragma unroll
    for (int mt = 0; mt < 4; mt++)
#pragma unroll
        for (int nt = 0; nt < 4; nt++)
#pragma unroll
            for (int r = 0; r < 4; r++) {
                int m = m0 + mo + mt * 16 + lg * 4 + r;
                int n = n0 + no + nt * 16 + l15;
                out[(size_t)m * DM + n] = acc[mt][nt][r] + bv4[nt];
            }
}

// ---------------------------------------------------------------------------
// Flash attention, bf16 MFMA. Block = (qblock of 256 rows) x (b,h), 512 thr.
// 8 waves; wave w owns q rows [w*32, w*32+32) (NQT=2). kv tiles of 64.
// STAGING (round-9): K/V tiles live in LINEAR [64][64] LDS, double-buffered,
// filled by async global_load_lds width-16 (zero data VGPRs -> no spill;
// rounds 3 & 8 proved reg-held staging spills at this kernel's 64-VGPR pin).
// Tile t+1 prefetches into buf^1 at the top of tile t's compute; the single
// end-of-iteration __syncthreads() (drains vmcnt) retires both directions.
// ONE barrier per tile (was two).
// Bank conflicts (rule #21 both-sides swizzle): linear 128B rows would be
// 16-way on ds_read_b128; global SOURCE is pre-swizzled per-lane
// (chunk = (l&7) ^ (row&7), lane-constant) and reads XOR the same way
// (co = (lg ^ (l15&7))*8) -> 2 lanes/16B slot = free.
// S^T = K·Q^T; softmax exp2-domain; bit-packed mask; defer-max (THR=0).
// l via ones-column MFMA (Osum = P·1). Pw swizzled, wave-private.
// ---------------------------------------------------------------------------
__global__ __launch_bounds__(512, 4) void attn_kernel(
    const unsigned short* __restrict__ qw, const unsigned short* __restrict__ kw,
    const unsigned short* __restrict__ vtw,
    const unsigned long long* __restrict__ mb,
    unsigned short* __restrict__ ao)   // [B,S,512] bf16
{
    __shared__ __align__(16) unsigned short Kb[2][64 * 64];   // linear, swizzled content
    __shared__ __align__(16) unsigned short Vb[2][64 * 64];   // linear, swizzled content
    __shared__ __align__(16) unsigned short Pw[8 * 32 * 64];  // per-wave [q][kv] swizzled
    const int t = threadIdx.x;
    const int w = t >> 6, l = t & 63;
    const int l15 = l & 15, lg = l >> 4;
    const int q0 = blockIdx.x * 256;
    const int bh = blockIdx.y;
    const int b = bh >> 3, h = bh & 7;
    const int q0w = q0 + w * 32;
    const unsigned short* qb = qw + (size_t)bh * SS * DKK;
    const unsigned short* kb = kw + (size_t)bh * SS * DKK;
    const unsigned short* vtb = vtw + (size_t)bh * DKK * SS;

    // --- staging geometry: wave w fills rows [w*8, w*8+8) (1 KB) per buffer.
    // LDS write is linear (base + lane*16); global src pre-swizzled.
    const int srow = (w << 3) | (l >> 3);              // 0..63
    const int schunk = (l & 7) ^ (srow & 7);           // swizzled 16B chunk
    const size_t koff = (size_t)srow * DKK + schunk * 8;  // shorts into K panel
    const size_t voff = (size_t)srow * SS + schunk * 8;   // shorts into V^T panel
    const int ldsbase = w * 512;                        // shorts (1 KB per wave)
    // --- read-side swizzled chunk offsets (lane constants) ---
    const int co0 = ((lg ^ (l15 & 7)) * 8);            // first 16B chunk
    const int co1 = (((4 + lg) ^ (l15 & 7)) * 8);      // second 16B chunk

    // Per-qt bit-mask row base (row = q0w + qt*16 + l15; 32 words per row)
    const unsigned long long* mbq[2];
#pragma unroll
    for (int qt = 0; qt < 2; qt++)
        mbq[qt] = mb + ((size_t)(q0w + qt * 16 + l15) << 5);

    // Q fragments (B-operand): Qf[qt][dh] = Q[q0w+qt*16+l15][dh*32+lg*8 ..+8]
    bf16x8 Qf[2][2];
#pragma unroll
    for (int qt = 0; qt < 2; qt++)
#pragma unroll
        for (int dh = 0; dh < 2; dh++)
            Qf[qt][dh] = *(const bf16x8*)(qb + (size_t)(q0w + qt * 16 + l15) * DKK + dh * 32 + lg * 8);

    f32x4 O[2][4];    // [qt][dt]: row q = qt*16+lg*4+r, col d = dt*16+l15
    f32x4 Osum[2];    // ones-column accumulator: row sums of P (l denominator)
#pragma unroll
    for (int i = 0; i < 2; i++) {
#pragma unroll
        for (int j = 0; j < 4; j++) O[i][j] = (f32x4){0.f, 0.f, 0.f, 0.f};
        Osum[i] = (f32x4){0.f, 0.f, 0.f, 0.f};
    }
    float m_i[2];
#pragma unroll
    for (int i = 0; i < 2; i++) m_i[i] = -INFINITY;

    const bf16x8 vone = {16256, 16256, 16256, 16256, 16256, 16256, 16256, 16256}; // bf16 1.0 x8
    const int pbase = w * 2048;

    // ---- prologue: async-stage tile 0 into buffer 0 ----
    GLL16(kb + koff, &Kb[0][ldsbase]);
    GLL16(vtb + voff, &Vb[0][ldsbase]);
    __syncthreads();   // drains vmcnt (gll) + barrier

    int cur = 0;
    for (int kv0 = 0; kv0 < SS; kv0 += 64) {
        // ---- prefetch tile t+1 into the alternate buffer (async, no VGPRs);
        //      completes at this iteration's ending __syncthreads ----
        if (kv0 + 64 < SS) {
            GLL16(kb + (size_t)(kv0 + 64) * DKK + koff, &Kb[cur ^ 1][ldsbase]);
            GLL16(vtb + (kv0 + 64) + voff, &Vb[cur ^ 1][ldsbase]);
        }

        // ---- S^T = K·Q^T : S[kvt][qt], row kv = kvt*16+lg*4+r, col q = qt*16+l15
        const unsigned short* Kc = &Kb[cur][0];
        const unsigned short* Vc = &Vb[cur][0];
        f32x4 S[4][2];
#pragma unroll
        for (int kvt = 0; kvt < 4; kvt++) {
            bf16x8 ak0 = *(const bf16x8*)&Kc[(kvt * 16 + l15) * 64 + co0];
            bf16x8 ak1 = *(const bf16x8*)&Kc[(kvt * 16 + l15) * 64 + co1];
#pragma unroll
            for (int qt = 0; qt < 2; qt++) {
                f32x4 z = (f32x4){0.f, 0.f, 0.f, 0.f};
                z = MFMA16(ak0, Qf[qt][0], z);
                z = MFMA16(ak1, Qf[qt][1], z);
                S[kvt][qt] = z;
            }
        }

        // ---- mask via packed bits: bit kv_local = kvt*16 + lg*4 + r ----
#pragma unroll
        for (int qt = 0; qt < 2; qt++) {
            unsigned long long mm = mbq[qt][kv0 >> 6];
            unsigned int wlo = (unsigned int)mm;
            unsigned int whi = (unsigned int)(mm >> 32);
            unsigned int u[4];
            u[0] = wlo >> (lg * 4);
            u[1] = wlo >> (16 + lg * 4);
            u[2] = whi >> (lg * 4);
            u[3] = whi >> (16 + lg * 4);
#pragma unroll
            for (int kvt = 0; kvt < 4; kvt++) {
                if (!(u[kvt] & 1u)) S[kvt][qt][0] = -1e38f;
                if (!(u[kvt] & 2u)) S[kvt][qt][1] = -1e38f;
                if (!(u[kvt] & 4u)) S[kvt][qt][2] = -1e38f;
                if (!(u[kvt] & 8u)) S[kvt][qt][3] = -1e38f;
            }
        }

        // ---- online softmax (exp2 domain) with defer-max (THR=0) ----
        float mtl[2];
#pragma unroll
        for (int qt = 0; qt < 2; qt++) {
            // balanced max3 tree over the 16 values (v_max3_f32 fusion)
            float mt = fmaxf(
                max3f(max3f(S[0][qt][0], S[0][qt][1], S[0][qt][2]),
                      max3f(S[0][qt][3], S[1][qt][0], S[1][qt][1]),
                      max3f(S[1][qt][2], S[1][qt][3], S[2][qt][0])),
                fmaxf(max3f(S[2][qt][1], S[2][qt][2], S[2][qt][3]),
                      max3f(S[3][qt][0], S[3][qt][1], fmaxf(S[3][qt][2], S[3][qt][3]))));
            mt = fmaxf(mt, __shfl_xor(mt, 16));
            mt = fmaxf(mt, __shfl_xor(mt, 32));
            mtl[qt] = mt;
        }
        int grow = (mtl[0] > m_i[0]) | (mtl[1] > m_i[1]);
        if (__any(grow)) {
            float alpha[2];
#pragma unroll
            for (int qt = 0; qt < 2; qt++) {
                float mn = fmaxf(m_i[qt], mtl[qt]);
                alpha[qt] = EXP2(m_i[qt] - mn);
                m_i[qt] = mn;
            }
            // rescale O and Osum by alpha (broadcast from q-col lanes to q-row regs)
#pragma unroll
            for (int qt = 0; qt < 2; qt++)
#pragma unroll
                for (int r = 0; r < 4; r++) {
                    float a = __shfl(alpha[qt], lg * 4 + r);
#pragma unroll
                    for (int dt = 0; dt < 4; dt++) O[qt][dt][r] *= a;
                    Osum[qt][r] *= a;
                }
        }

#pragma unroll
        for (int qt = 0; qt < 2; qt++) {
            const int prow = qt * 16 + l15;
            const int swz = (prow & 7) << 3;
#pragma unroll
            for (int kvt = 0; kvt < 4; kvt++) {
                float p0 = EXP2(S[kvt][qt][0] - m_i[qt]);
                float p1 = EXP2(S[kvt][qt][1] - m_i[qt]);
                float p2 = EXP2(S[kvt][qt][2] - m_i[qt]);
                float p3 = EXP2(S[kvt][qt][3] - m_i[qt]);
                bf16x4 pk;
                pk[0] = (short)f2bf(p0); pk[1] = (short)f2bf(p1);
                pk[2] = (short)f2bf(p2); pk[3] = (short)f2bf(p3);
                *(bf16x4*)&Pw[pbase + prow * 64 + ((kvt * 16 + lg * 4) ^ swz)] = pk;
            }
        }

        // Pw is wave-private: per-wave DS ops complete in order, so a block
        // barrier is unnecessary. The fence stops the compiler from hoisting
        // the ap reads above the pk stores.
        asm volatile("s_waitcnt lgkmcnt(0)" ::: "memory");

        // ---- O += P·V ; Osum += P·1 (row sums == softmax denominator) ----
        bf16x8 bv2[4][2];
#pragma unroll
        for (int dt = 0; dt < 4; dt++) {
            bv2[dt][0] = *(const bf16x8*)&Vc[(dt * 16 + l15) * 64 + co0];
            bv2[dt][1] = *(const bf16x8*)&Vc[(dt * 16 + l15) * 64 + co1];
        }
#pragma unroll
        for (int qt = 0; qt < 2; qt++) {
            const int prow = qt * 16 + l15;
            const int swz = (prow & 7) << 3;
            bf16x8 ap0 = *(const bf16x8*)&Pw[pbase + prow * 64 + ((lg * 8) ^ swz)];
            bf16x8 ap1 = *(const bf16x8*)&Pw[pbase + prow * 64 + ((32 + lg * 8) ^ swz)];
#pragma unroll
            for (int dt = 0; dt < 4; dt++) {
                O[qt][dt] = MFMA16(ap0, bv2[dt][0], O[qt][dt]);
                O[qt][dt] = MFMA16(ap1, bv2[dt][1], O[qt][dt]);
            }
            Osum[qt] = MFMA16(ap0, vone, Osum[qt]);
            Osum[qt] = MFMA16(ap1, vone, Osum[qt]);
        }

        // single barrier: (a) retires this tile's reads of buf[cur] before
        // it is overwritten next iteration, (b) drains vmcnt so the prefetch
        // into buf[cur^1] is complete before anyone reads it.
        __syncthreads();
        cur ^= 1;
    }

    // ---- epilogue: normalize by Osum (per-lane, no shfl), store bf16 ----
#pragma unroll
    for (int qt = 0; qt < 2; qt++) {
#pragma unroll
        for (int r = 0; r < 4; r++) {
            float lv = 1.f / Osum[qt][r];
            int q = q0w + qt * 16 + lg * 4 + r;
            size_t base = ((size_t)b * SS + q) * DM + h * 64;
#pragma unroll
            for (int dt = 0; dt < 4; dt++)
                ao[base + dt * 16 + l15] = f2bf(O[qt][dt][r] * lv);
        }
    }
}

extern "C" void kernel_launch(void* const* d_in, const int* in_sizes, int n_in,
                              void* d_out, int out_size, void* d_ws, size_t ws_size,
                              hipStream_t stream) {
    // All float tensors are fp32 (proven). mask is int32.
    const float* Q    = (const float*)d_in[0];
    const float* K    = (const float*)d_in[1];
    const float* V    = (const float*)d_in[2];
    const int*   mask = (const int*)d_in[3];
    const float* Wq   = (const float*)d_in[4];
    const float* bq   = (const float*)d_in[5];
    const float* Wk   = (const float*)d_in[6];
    const float* bk   = (const float*)d_in[7];
    const float* Wv   = (const float*)d_in[8];
    const float* bv   = (const float*)d_in[9];
    const float* Wo   = (const float*)d_in[10];
    const float* bo   = (const float*)d_in[11];

    // ws: [qb 16 MB][kb 16 MB][vtb 16 MB][ab 16 MB] = 64 MB (proven-safe).
    // vtb holds V ALREADY TRANSPOSED ([bh][64][S]). ab head doubles as the
    // bf16-W scratch (1.5 MB): written by w_cvt, read by proj_qkv_fused,
    // then fully overwritten by attn's output (stream-ordered, safe).
    const size_t SEG = (size_t)BB * HH * SS * DKK;  // 8,388,608 bf16 elems
    unsigned short* qb  = (unsigned short*)d_ws;
    unsigned short* kb  = qb + SEG;
    unsigned short* vtb = kb + SEG;
    unsigned short* ab  = vtb + SEG;
    unsigned short* wb  = ab;   // 3 x 262144 bf16 = 1.5 MB, dead before attn

    const size_t MB_BYTES = (size_t)SS * (SS / 64) * sizeof(unsigned long long); // 524288
    unsigned long long* mbits =
        (unsigned long long*)((char*)d_out + (size_t)out_size - MB_BYTES);

    const float qscale = 0.125f * 1.44269504088896340736f;  // 1/sqrt(dk) * log2(e)

    mask_pack<<<dim3((SS * (SS / 64)) / 4), 256, 0, stream>>>(mask, mbits);
    w_cvt<<<dim3(384), 256, 0, stream>>>(Wq, Wk, Wv, wb);

    dim3 gp(DM / 128, (BB * SS) / 128, 3);  // (4, 128, 3)
    proj_qkv_fused<<<gp, 256, 0, stream>>>(Q, K, V, wb, bq, bk, bv, qb, qscale);

    attn_kernel<<<dim3(SS / 256, BB * HH), 512, 0, stream>>>(qb, kb, vtb, mbits, ab);

    proj_out_mfma<<<dim3(DM / 128, (BB * SS) / 128), 256, 0, stream>>>(ab, Wo, bo, (float*)d_out);
}

// Round 10
// 384.163 us; speedup vs baseline: 1.0817x; 1.0084x over previous
//
#include <hip/hip_runtime.h>
#include <hip/hip_bf16.h>
#include <math.h>

#define BB 8
#define SS 2048
#define HH 8
#define DKK 64
#define DM 512

typedef short bf16x8 __attribute__((ext_vector_type(8)));
typedef short bf16x4 __attribute__((ext_vector_type(4)));
typedef float f32x4 __attribute__((ext_vector_type(4)));
#define MFMA16(a, b, c) __builtin_amdgcn_mfma_f32_16x16x32_bf16(a, b, c, 0, 0, 0)

#if __has_builtin(__builtin_amdgcn_exp2f)
#define EXP2(x) __builtin_amdgcn_exp2f(x)
#else
#define EXP2(x) exp2f(x)
#endif

// async global->LDS, 16B per lane; lds dest must be wave-uniform base
// (HW writes base + lane*16). Global src IS per-lane (pre-swizzled).
#define GLL16(gsrc, ldst)                                                      \
    __builtin_amdgcn_global_load_lds(                                          \
        (const __attribute__((address_space(1))) unsigned int*)(gsrc),         \
        (__attribute__((address_space(3))) unsigned int*)(ldst), 16, 0, 0)

__device__ __forceinline__ unsigned short f2bf(float f) {
    __hip_bfloat16 h = __float2bfloat16(f);
    return *reinterpret_cast<unsigned short*>(&h);
}

__device__ __forceinline__ float max3f(float a, float b, float c) {
    return fmaxf(fmaxf(a, b), c);   // clang fuses to v_max3_f32
}

// Convert 8 consecutive fp32 -> 8 bf16, return as uint4 for a 16B LDS store.
__device__ __forceinline__ uint4 cvt8(const float* __restrict__ src) {
    float4 a = *(const float4*)src;
    float4 b = *(const float4*)(src + 4);
    unsigned short tmp[8];
    tmp[0] = f2bf(a.x); tmp[1] = f2bf(a.y); tmp[2] = f2bf(a.z); tmp[3] = f2bf(a.w);
    tmp[4] = f2bf(b.x); tmp[5] = f2bf(b.y); tmp[6] = f2bf(b.z); tmp[7] = f2bf(b.w);
    return *(uint4*)tmp;
}

// ---------------------------------------------------------------------------
// Prep (merged mask_pack + w_cvt, one launch):
// blocks [0,16384): mask int32 [S][S] -> mb uint64 [S][S/64] via __ballot.
// blocks [16384,16768): Wq/Wk/Wv fp32 -> bf16 packed into wdst (1.5 MB).
// ---------------------------------------------------------------------------
__global__ __launch_bounds__(256) void prep_kernel(
    const int* __restrict__ mask, unsigned long long* __restrict__ mb,
    const float* __restrict__ Wq, const float* __restrict__ Wk,
    const float* __restrict__ Wv, unsigned short* __restrict__ wdst)
{
    const int bid = blockIdx.x;
    const int t = threadIdx.x;
    if (bid < 16384) {
        const int wid = (bid << 2) | (t >> 6);   // global wave id == word idx
        const int lane = t & 63;
        const int q = wid >> 5;                   // / (SS/64)
        const int c = wid & 31;
        int e = mask[(size_t)q * SS + (c << 6) + lane];
        unsigned long long bal = __ballot(e != 0);
        if (lane == 0) mb[wid] = bal;
    } else {
        const int idx = (bid - 16384) * 256 + t;  // 0..98303
        const int which = idx >> 15;              // / 32768
        const int off = (idx & 32767) * 8;
        const float* src = (which == 0) ? Wq : (which == 1) ? Wk : Wv;
        *(uint4*)(wdst + (size_t)which * 262144 + off) = cvt8(src + off);
    }
}

// ---------------------------------------------------------------------------
// Fused QKV projection (gridDim.z selects Q/K/V): out[m][n] =
// (sum_k X[m][k]*W[n][k] + bias[n]) * scale.
// W (pre-converted bf16) staged via async global_load_lds width-16 into a
// LINEAR Ws[128*64] with rule-21 both-sides swizzle: source chunk
// (l&7)^(row&7), read chunk (lg)^(l15&7) — pattern proven in round-9 attn.
// Zero data VGPRs on the W panel. X is fp32: cvt8 staging into padded Xs.
// z=0 (Q), z=1 (K): out bf16 scattered to [B*H][S][64] (n = h*64+d).
// z=2 (V): out written TRANSPOSED to [B*H][64][S].
// ---------------------------------------------------------------------------
__global__ __launch_bounds__(256, 2) void proj_qkv_fused(
    const float* __restrict__ Xq, const float* __restrict__ Xk, const float* __restrict__ Xv,
    const unsigned short* __restrict__ Wb,
    const float* __restrict__ bq, const float* __restrict__ bk, const float* __restrict__ bv,
    unsigned short* __restrict__ outbase, float qscale)
{
    const int z = blockIdx.z;
    const float* X = (z == 0) ? Xq : (z == 1) ? Xk : Xv;
    const unsigned short* W = Wb + (size_t)z * 262144;
    const float* bias = (z == 0) ? bq : (z == 1) ? bk : bv;
    unsigned short* out = outbase + (size_t)z * ((size_t)BB * HH * SS * DKK);
    const float scale = (z == 0) ? qscale : 1.0f;

    __shared__ __align__(16) unsigned short Xs[128][72];
    __shared__ __align__(16) unsigned short Ws[128 * 64];   // linear, swizzled content
    const int t = threadIdx.x;
    const int w = t >> 6, l = t & 63;
    const int l15 = l & 15, lg = l >> 4;
    const int n0 = blockIdx.x * 128, m0 = blockIdx.y * 128;
    const int mo = (w & 1) * 64, no = (w >> 1) * 64;
    const int rsw = l15 & 7;                 // read-side row swizzle key

    f32x4 acc[4][4];
#pragma unroll
    for (int i = 0; i < 4; i++)
#pragma unroll
        for (int j = 0; j < 4; j++) acc[i][j] = (f32x4){0.f, 0.f, 0.f, 0.f};

    for (int k0 = 0; k0 < DM; k0 += 64) {
        __syncthreads();
        // ---- W: async gll16, wave w covers rows [w*32, w*32+32) in 4 segs
        //      of 8 rows (64 lanes x 16B = 8 rows x 64 shorts each) ----
#pragma unroll
        for (int s = 0; s < 4; s++) {
            int row = (w << 5) + (s << 3) + (l >> 3);
            int schunk = (l & 7) ^ (row & 7);
            GLL16(W + (size_t)(n0 + row) * DM + k0 + schunk * 8,
                  &Ws[((w << 5) + (s << 3)) << 6]);
        }
        // ---- X: fp32 -> bf16 cvt staging (padded rows) ----
#pragma unroll
        for (int rr = 0; rr < 4; rr++) {
            int idx = rr * 2048 + t * 8;
            int row = idx >> 6, col = idx & 63;
            *(uint4*)&Xs[row][col] = cvt8(X + (size_t)(m0 + row) * DM + k0 + col);
        }
        __syncthreads();   // drains lgkm (Xs writes) + vmcnt (gll16)

        bf16x8 af[4][2], bfr[4][2];
#pragma unroll
        for (int mt = 0; mt < 4; mt++) {
            af[mt][0] = *(const bf16x8*)&Xs[mo + mt * 16 + l15][lg * 8];
            af[mt][1] = *(const bf16x8*)&Xs[mo + mt * 16 + l15][32 + lg * 8];
        }
#pragma unroll
        for (int nt = 0; nt < 4; nt++) {
            const int wrow = (no + nt * 16 + l15) << 6;
            bfr[nt][0] = *(const bf16x8*)&Ws[wrow + ((lg ^ rsw) << 3)];
            bfr[nt][1] = *(const bf16x8*)&Ws[wrow + (((4 + lg) ^ rsw) << 3)];
        }
#pragma unroll
        for (int mt = 0; mt < 4; mt++)
#pragma unroll
            for (int nt = 0; nt < 4; nt++) {
                acc[mt][nt] = MFMA16(af[mt][0], bfr[nt][0], acc[mt][nt]);
                acc[mt][nt] = MFMA16(af[mt][1], bfr[nt][1], acc[mt][nt]);
            }
    }

    float bv4[4];
#pragma unroll
    for (int nt = 0; nt < 4; nt++) bv4[nt] = bias[n0 + no + nt * 16 + l15];

    const int h = (n0 + no) >> 6;
    if (z == 2) {
        // transposed V epilogue: vt[bh][d][s]
#pragma unroll
        for (int mt = 0; mt < 4; mt++) {
            int m = m0 + mo + mt * 16 + lg * 4;       // 4-aligned, never crosses b
            int bb = m >> 11, s = m & (SS - 1);
#pragma unroll
            for (int nt = 0; nt < 4; nt++) {
                int d = nt * 16 + l15;
                bf16x4 pk;
#pragma unroll
                for (int r = 0; r < 4; r++) pk[r] = (short)f2bf(acc[mt][nt][r] + bv4[nt]);
                *(bf16x4*)(out + (((size_t)bb * HH + h) * DKK + d) * SS + s) = pk;
            }
        }
    } else {
#pragma unroll
        for (int mt = 0; mt < 4; mt++)
#pragma unroll
            for (int nt = 0; nt < 4; nt++)
#pragma unroll
                for (int r = 0; r < 4; r++) {
                    int m = m0 + mo + mt * 16 + lg * 4 + r;
                    int d = nt * 16 + l15;
                    float v = (acc[mt][nt][r] + bv4[nt]) * scale;
                    int bb = m >> 11, s = m & (SS - 1);
                    out[(((size_t)bb * HH + h) * SS + s) * 64 + d] = f2bf(v);
                }
    }
}

// ---------------------------------------------------------------------------
// Output projection: out[m][n] = sum_k A[m][k]*Wo[n][k] + bo[n]
// A bf16 [16384,512] (ws), Wo fp32 [512,512], out fp32 row-major (d_out).
// ---------------------------------------------------------------------------
__global__ __launch_bounds__(256, 2) void proj_out_mfma(
    const unsigned short* __restrict__ Xb,
    const float* __restrict__ W,
    const float* __restrict__ bias,
    float* __restrict__ out)
{
    __shared__ __align__(16) unsigned short Xs[128][72];
    __shared__ __align__(16) unsigned short Ws[128][72];
    const int t = threadIdx.x;
    const int w = t >> 6, l = t & 63;
    const int l15 = l & 15, lg = l >> 4;
    const int n0 = blockIdx.x * 128, m0 = blockIdx.y * 128;
    const int mo = (w & 1) * 64, no = (w >> 1) * 64;

    f32x4 acc[4][4];
#pragma unroll
    for (int i = 0; i < 4; i++)
#pragma unroll
        for (int j = 0; j < 4; j++) acc[i][j] = (f32x4){0.f, 0.f, 0.f, 0.f};

    for (int k0 = 0; k0 < DM; k0 += 64) {
        __syncthreads();
#pragma unroll
        for (int rr = 0; rr < 4; rr++) {
            int idx = rr * 2048 + t * 8;
            int row = idx >> 6, col = idx & 63;
            *(uint4*)&Xs[row][col] = *(const uint4*)(Xb + (size_t)(m0 + row) * DM + k0 + col);
            *(uint4*)&Ws[row][col] = cvt8(W + (size_t)(n0 + row) * DM + k0 + col);
        }
        __syncthreads();

        bf16x8 af[4][2], bfr[4][2];
#pragma unroll
        for (int mt = 0; mt < 4; mt++) {
            af[mt][0] = *(const bf16x8*)&Xs[mo + mt * 16 + l15][lg * 8];
            af[mt][1] = *(const bf16x8*)&Xs[mo + mt * 16 + l15][32 + lg * 8];
        }
#pragma unroll
        for (int nt = 0; nt < 4; nt++) {
            bfr[nt][0] = *(const bf16x8*)&Ws[no + nt * 16 + l15][lg * 8];
            bfr[nt][1] = *(const bf16x8*)&Ws[no + nt * 16 + l15][32 + lg * 8];
        }
#pragma unroll
        for (int mt = 0; mt < 4; mt++)
#pragma unroll
            for (int nt = 0; nt < 4; nt++) {
                acc[mt][nt] = MFMA16(af[mt][0], bfr[nt][0], acc[mt][nt]);
                acc[mt][nt] = MFMA16(af[mt][1], bfr[nt][1], acc[mt][nt]);
            }
    }

    float bv4[4];
#pragma unroll
    for (int nt = 0; nt < 4; nt++) bv4[nt] = bias[n0 + no + nt * 16 + l15];

#pragma unroll
    for (int mt = 0; mt < 4; mt++)
#pragma unroll
        for (int nt = 0; nt < 4; nt++)
#pragma unroll
            for (int r = 0; r < 4; r++) {
                int m = m0 + mo + mt * 16 + lg * 4 + r;
                int n = n0 + no + nt * 16 + l15;
                out[(size_t)m * DM + n] = acc[mt][nt][r] + bv4[nt];
            }
}

// ---------------------------------------------------------------------------
// Flash attention, bf16 MFMA — EXACT round-7 structure (best measured:
// 146.5 µs). Block = (qblock of 256 rows) x (b,h), 512 thr, 8 waves; wave w
// owns q rows [w*32, w*32+32) (NQT=2). kv tiles of 64, simple 2-barrier
// staging (1 uint4/thread/buffer). Round-8 reg-prefetch spilled (VGPR pin
// 64); round-9 gll16-dbuf was −5% despite fewer conflicts -> staging is NOT
// the critical path; keep the simple proven form.
// S^T = K·Q^T; softmax exp2-domain; bit-packed mask; defer-max (THR=0).
// l via ones-column MFMA (Osum = P·1). Pw swizzled, wave-private.
// ---------------------------------------------------------------------------
__global__ __launch_bounds__(512, 4) void attn_kernel(
    const unsigned short* __restrict__ qw, const unsigned short* __restrict__ kw,
    const unsigned short* __restrict__ vtw,
    const unsigned long long* __restrict__ mb,
    unsigned short* __restrict__ ao)   // [B,S,512] bf16
{
    __shared__ __align__(16) unsigned short Ks[64][72];   // [kv][d]
    __shared__ __align__(16) unsigned short Vt[64][72];   // [d][kv]
    __shared__ __align__(16) unsigned short Pw[8 * 32 * 64]; // per-wave [q][kv] swizzled
    const int t = threadIdx.x;
    const int w = t >> 6, l = t & 63;
    const int l15 = l & 15, lg = l >> 4;
    const int q0 = blockIdx.x * 256;
    const int bh = blockIdx.y;
    const int b = bh >> 3, h = bh & 7;
    const int q0w = q0 + w * 32;
    const unsigned short* qb = qw + (size_t)bh * SS * DKK;
    const unsigned short* kb = kw + (size_t)bh * SS * DKK;
    const unsigned short* vtb = vtw + (size_t)bh * DKK * SS;

    // Per-qt bit-mask row base (row = q0w + qt*16 + l15; 32 words per row)
    const unsigned long long* mbq[2];
#pragma unroll
    for (int qt = 0; qt < 2; qt++)
        mbq[qt] = mb + ((size_t)(q0w + qt * 16 + l15) << 5);

    // Q fragments (B-operand): Qf[qt][dh] = Q[q0w+qt*16+l15][dh*32+lg*8 ..+8]
    bf16x8 Qf[2][2];
#pragma unroll
    for (int qt = 0; qt < 2; qt++)
#pragma unroll
        for (int dh = 0; dh < 2; dh++)
            Qf[qt][dh] = *(const bf16x8*)(qb + (size_t)(q0w + qt * 16 + l15) * DKK + dh * 32 + lg * 8);

    f32x4 O[2][4];    // [qt][dt]: row q = qt*16+lg*4+r, col d = dt*16+l15
    f32x4 Osum[2];    // ones-column accumulator: row sums of P (l denominator)
#pragma unroll
    for (int i = 0; i < 2; i++) {
#pragma unroll
        for (int j = 0; j < 4; j++) O[i][j] = (f32x4){0.f, 0.f, 0.f, 0.f};
        Osum[i] = (f32x4){0.f, 0.f, 0.f, 0.f};
    }
    float m_i[2];
#pragma unroll
    for (int i = 0; i < 2; i++) m_i[i] = -INFINITY;

    const bf16x8 vone = {16256, 16256, 16256, 16256, 16256, 16256, 16256, 16256}; // bf16 1.0 x8
    const int pbase = w * 2048;

    for (int kv0 = 0; kv0 < SS; kv0 += 64) {
        __syncthreads();   // all waves done with Ks/Vt of previous tile
        // ---- stage K tile + (pre-transposed) V tile: 1 uint4/thread each ----
        {
            int idx = t * 8;                 // 512 threads x 8 shorts = 64x64
            int row = idx >> 6, col = idx & 63;
            *(uint4*)&Ks[row][col] = *(const uint4*)(kb + (size_t)(kv0 + row) * DKK + col);
            *(uint4*)&Vt[row][col] = *(const uint4*)(vtb + (size_t)row * SS + kv0 + col);
        }
        __syncthreads();

        // ---- S^T = K·Q^T : S[kvt][qt], row kv = kvt*16+lg*4+r, col q = qt*16+l15
        f32x4 S[4][2];
#pragma unroll
        for (int kvt = 0; kvt < 4; kvt++) {
            bf16x8 ak0 = *(const bf16x8*)&Ks[kvt * 16 + l15][lg * 8];
            bf16x8 ak1 = *(const bf16x8*)&Ks[kvt * 16 + l15][32 + lg * 8];
#pragma unroll
            for (int qt = 0; qt < 2; qt++) {
                f32x4 z = (f32x4){0.f, 0.f, 0.f, 0.f};
                z = MFMA16(ak0, Qf[qt][0], z);
                z = MFMA16(ak1, Qf[qt][1], z);
                S[kvt][qt] = z;
            }
        }

        // ---- mask via packed bits: bit kv_local = kvt*16 + lg*4 + r ----
#pragma unroll
        for (int qt = 0; qt < 2; qt++) {
            unsigned long long mm = mbq[qt][kv0 >> 6];
            unsigned int wlo = (unsigned int)mm;
            unsigned int whi = (unsigned int)(mm >> 32);
            unsigned int u[4];
            u[0] = wlo >> (lg * 4);
            u[1] = wlo >> (16 + lg * 4);
            u[2] = whi >> (lg * 4);
            u[3] = whi >> (16 + lg * 4);
#pragma unroll
            for (int kvt = 0; kvt < 4; kvt++) {
                if (!(u[kvt] & 1u)) S[kvt][qt][0] = -1e38f;
                if (!(u[kvt] & 2u)) S[kvt][qt][1] = -1e38f;
                if (!(u[kvt] & 4u)) S[kvt][qt][2] = -1e38f;
                if (!(u[kvt] & 8u)) S[kvt][qt][3] = -1e38f;
            }
        }

        // ---- online softmax (exp2 domain) with defer-max (THR=0) ----
        float mtl[2];
#pragma unroll
        for (int qt = 0; qt < 2; qt++) {
            // balanced max3 tree over the 16 values (v_max3_f32 fusion)
            float mt = fmaxf(
                max3f(max3f(S[0][qt][0], S[0][qt][1], S[0][qt][2]),
                      max3f(S[0][qt][3], S[1][qt][0], S[1][qt][1]),
                      max3f(S[1][qt][2], S[1][qt][3], S[2][qt][0])),
                fmaxf(max3f(S[2][qt][1], S[2][qt][2], S[2][qt][3]),
                      max3f(S[3][qt][0], S[3][qt][1], fmaxf(S[3][qt][2], S[3][qt][3]))));
            mt = fmaxf(mt, __shfl_xor(mt, 16));
            mt = fmaxf(mt, __shfl_xor(mt, 32));
            mtl[qt] = mt;
        }
        int grow = (mtl[0] > m_i[0]) | (mtl[1] > m_i[1]);
        if (__any(grow)) {
            float alpha[2];
#pragma unroll
            for (int qt = 0; qt < 2; qt++) {
                float mn = fmaxf(m_i[qt], mtl[qt]);
                alpha[qt] = EXP2(m_i[qt] - mn);
                m_i[qt] = mn;
            }
            // rescale O and Osum by alpha (broadcast from q-col lanes to q-row regs)
#pragma unroll
            for (int qt = 0; qt < 2; qt++)
#pragma unroll
                for (int r = 0; r < 4; r++) {
                    float a = __shfl(alpha[qt], lg * 4 + r);
#pragma unroll
                    for (int dt = 0; dt < 4; dt++) O[qt][dt][r] *= a;
                    Osum[qt][r] *= a;
                }
        }

#pragma unroll
        for (int qt = 0; qt < 2; qt++) {
            const int prow = qt * 16 + l15;
            const int swz = (prow & 7) << 3;
#pragma unroll
            for (int kvt = 0; kvt < 4; kvt++) {
                float p0 = EXP2(S[kvt][qt][0] - m_i[qt]);
                float p1 = EXP2(S[kvt][qt][1] - m_i[qt]);
                float p2 = EXP2(S[kvt][qt][2] - m_i[qt]);
                float p3 = EXP2(S[kvt][qt][3] - m_i[qt]);
                bf16x4 pk;
                pk[0] = (short)f2bf(p0); pk[1] = (short)f2bf(p1);
                pk[2] = (short)f2bf(p2); pk[3] = (short)f2bf(p3);
                *(bf16x4*)&Pw[pbase + prow * 64 + ((kvt * 16 + lg * 4) ^ swz)] = pk;
            }
        }

        // Pw is wave-private: per-wave DS ops complete in order, so a block
        // barrier is unnecessary. The fence stops the compiler from hoisting
        // the ap reads above the pk stores.
        asm volatile("s_waitcnt lgkmcnt(0)" ::: "memory");

        // ---- O += P·V ; Osum += P·1 (row sums == softmax denominator) ----
        bf16x8 bv2[4][2];
#pragma unroll
        for (int dt = 0; dt < 4; dt++) {
            bv2[dt][0] = *(const bf16x8*)&Vt[dt * 16 + l15][lg * 8];
            bv2[dt][1] = *(const bf16x8*)&Vt[dt * 16 + l15][32 + lg * 8];
        }
#pragma unroll
        for (int qt = 0; qt < 2; qt++) {
            const int prow = qt * 16 + l15;
            const int swz = (prow & 7) << 3;
            bf16x8 ap0 = *(const bf16x8*)&Pw[pbase + prow * 64 + ((lg * 8) ^ swz)];
            bf16x8 ap1 = *(const bf16x8*)&Pw[pbase + prow * 64 + ((32 + lg * 8) ^ swz)];
#pragma unroll
            for (int dt = 0; dt < 4; dt++) {
                O[qt][dt] = MFMA16(ap0, bv2[dt][0], O[qt][dt]);
                O[qt][dt] = MFMA16(ap1, bv2[dt][1], O[qt][dt]);
            }
            Osum[qt] = MFMA16(ap0, vone, Osum[qt]);
            Osum[qt] = MFMA16(ap1, vone, Osum[qt]);
        }
    }

    // ---- epilogue: normalize by Osum (per-lane, no shfl), store bf16 ----
#pragma unroll
    for (int qt = 0; qt < 2; qt++) {
#pragma unroll
        for (int r = 0; r < 4; r++) {
            float lv = 1.f / Osum[qt][r];
            int q = q0w + qt * 16 + lg * 4 + r;
            size_t base = ((size_t)b * SS + q) * DM + h * 64;
#pragma unroll
            for (int dt = 0; dt < 4; dt++)
                ao[base + dt * 16 + l15] = f2bf(O[qt][dt][r] * lv);
        }
    }
}

extern "C" void kernel_launch(void* const* d_in, const int* in_sizes, int n_in,
                              void* d_out, int out_size, void* d_ws, size_t ws_size,
                              hipStream_t stream) {
    // All float tensors are fp32 (proven). mask is int32.
    const float* Q    = (const float*)d_in[0];
    const float* K    = (const float*)d_in[1];
    const float* V    = (const float*)d_in[2];
    const int*   mask = (const int*)d_in[3];
    const float* Wq   = (const float*)d_in[4];
    const float* bq   = (const float*)d_in[5];
    const float* Wk   = (const float*)d_in[6];
    const float* bk   = (const float*)d_in[7];
    const float* Wv   = (const float*)d_in[8];
    const float* bv   = (const float*)d_in[9];
    const float* Wo   = (const float*)d_in[10];
    const float* bo   = (const float*)d_in[11];

    // ws: [qb 16 MB][kb 16 MB][vtb 16 MB][ab 16 MB] = 64 MB (proven-safe).
    // vtb holds V ALREADY TRANSPOSED ([bh][64][S]). ab head doubles as the
    // bf16-W scratch (1.5 MB): written by prep, read by proj_qkv_fused,
    // then fully overwritten by attn's output (stream-ordered, safe).
    const size_t SEG = (size_t)BB * HH * SS * DKK;  // 8,388,608 bf16 elems
    unsigned short* qb  = (unsigned short*)d_ws;
    unsigned short* kb  = qb + SEG;
    unsigned short* vtb = kb + SEG;
    unsigned short* ab  = vtb + SEG;
    unsigned short* wb  = ab;   // 3 x 262144 bf16 = 1.5 MB, dead before attn

    const size_t MB_BYTES = (size_t)SS * (SS / 64) * sizeof(unsigned long long); // 524288
    unsigned long long* mbits =
        (unsigned long long*)((char*)d_out + (size_t)out_size - MB_BYTES);

    const float qscale = 0.125f * 1.44269504088896340736f;  // 1/sqrt(dk) * log2(e)

    // merged mask_pack (16384 blocks) + w_cvt (384 blocks)
    prep_kernel<<<dim3(16384 + 384), 256, 0, stream>>>(mask, mbits, Wq, Wk, Wv, wb);

    dim3 gp(DM / 128, (BB * SS) / 128, 3);  // (4, 128, 3)
    proj_qkv_fused<<<gp, 256, 0, stream>>>(Q, K, V, wb, bq, bk, bv, qb, qscale);

    attn_kernel<<<dim3(SS / 256, BB * HH), 512, 0, stream>>>(qb, kb, vtb, mbits, ab);

    proj_out_mfma<<<dim3(DM / 128, (BB * SS) / 128), 256, 0, stream>>>(ab, Wo, bo, (float*)d_out);
}